// Round 21
// baseline (1420.650 us; speedup 1.0000x reference)
//
#include <hip/hip_runtime.h>

#define NN 50000
#define NE 800000
#define EPSV 1e-5f

typedef _Float16 f16;
typedef __attribute__((ext_vector_type(4)))  float f32x4;
typedef __attribute__((ext_vector_type(16))) float f32x16;
typedef __attribute__((ext_vector_type(8)))  f16 f16x8;
typedef __attribute__((ext_vector_type(4)))  f16 f16x4;

// permuted k order within each 16-group: quads [0,2,1,3] so each MFMA fragment
// is one contiguous 16B chunk. involution; preserves offset within a quad.
static __device__ __forceinline__ int kperm(int k){
  int q = (k>>2)&3;
  int p = ((q&1)<<1) | (q>>1);
  return (k & ~15) + (p<<2) + (k&3);
}

// chunk-panel-major address for GEMM operands (A=aggh, B=Wt):
// [panel = row>>8][k-chunk = kk>>3][row&255][kk&7], panel stride 256*K.
static __device__ __forceinline__ size_t cpm(int row, int kk, int K){
  return ((size_t)(row>>8))*256*K + ((size_t)(kk>>3))*2048 + (size_t)((row&255)*8) + (kk&7);
}

// ---------- degree / CSR build ----------
__global__ void k_init_deg(float* __restrict__ deg){
  int i = blockIdx.x*256 + threadIdx.x;
  if (i < NN) deg[i] = 1.0f;
}

__global__ void k_build(const int* __restrict__ ei, const float* __restrict__ ea,
                        int* __restrict__ cnt, float* __restrict__ deg){
  int e = blockIdx.x*256 + threadIdx.x;
  if (e < NE){
    int d = ei[NE + e];
    atomicAdd(&cnt[d], 1);
    atomicAdd(&deg[d], ea[3*e+2]);
  }
}

__global__ void k_fin_deg(const float* __restrict__ deg, float* __restrict__ dinv,
                          float* __restrict__ dinv2){
  int i = blockIdx.x*256 + threadIdx.x;
  if (i < NN){ float r = rsqrtf(deg[i]); dinv[i] = r; dinv2[i] = r*r; }
}

__global__ __launch_bounds__(1024) void k_scan(const int* __restrict__ cnt,
                                               int* __restrict__ rowptr,
                                               int* __restrict__ cursor){
  __shared__ int sums[1024];
  int t = threadIdx.x;
  int b0 = t*49, b1 = b0+49; if (b0 > NN) b0 = NN; if (b1 > NN) b1 = NN;
  int s = 0;
  for (int i = b0; i < b1; ++i) s += cnt[i];
  sums[t] = s; __syncthreads();
  for (int o = 1; o < 1024; o <<= 1){
    int v = (t >= o) ? sums[t-o] : 0;
    __syncthreads();
    sums[t] += v;
    __syncthreads();
  }
  int p = sums[t] - s;
  for (int i = b0; i < b1; ++i){ rowptr[i] = p; cursor[i] = p; p += cnt[i]; }
  if (t == 1023) rowptr[NN] = sums[1023];
}

__global__ void k_fill(const int* __restrict__ ei, const float* __restrict__ ea,
                       const float* __restrict__ dinv, int* __restrict__ cursor,
                       int* __restrict__ csrc, float* __restrict__ ccf){
  int e = blockIdx.x*256 + threadIdx.x;
  if (e < NE){
    int s = ei[e], d = ei[NE+e];
    float w = ea[3*e+2];
    int p = atomicAdd(&cursor[d], 1);
    csrc[p] = s;
    ccf[p] = dinv[s]*w*dinv[d];
  }
}

// ---------- x f32 -> fp16 (row-major, k-permuted; agg1 input) ----------
__global__ void k_xconv(const float* __restrict__ x, f16* __restrict__ xh){
  int idx = blockIdx.x*256 + threadIdx.x;      // quad index
  if (idx >= NN*64) return;
  int node = idx >> 6, k = (idx & 63)*4;
  f32x4 v = *(const f32x4*)(x + (size_t)node*256 + k);
  f16x4 h;
  #pragma unroll
  for (int j=0;j<4;++j) h[j] = (f16)v[j];
  *(f16x4*)(xh + (size_t)node*256 + kperm(k)) = h;
}

// ---------- W transpose -> fp16 chunk-panel-major [n-panel][kchunk][n][8] ----------
__global__ void k_w16(const float* __restrict__ W, f16* __restrict__ Wt,
                      int K, int M, int Mpad){
  int idx = blockIdx.x*256 + threadIdx.x;
  if (idx >= K*Mpad) return;
  int k = idx / Mpad, n = idx % Mpad;
  float v = (n < M) ? W[(size_t)k*M + n] : 0.f;
  Wt[cpm(n, kperm(k), K)] = (f16)v;
}

// ---------- BN affine precompute: av/bv per STORED column ----------
__global__ void k_bnpre(const float* __restrict__ s1, const float* __restrict__ s2,
                        const float* __restrict__ g, const float* __restrict__ be,
                        float* __restrict__ avp, float* __restrict__ bvp, int H){
  int c = blockIdx.x*256 + threadIdx.x;
  if (c >= H) return;
  int ac = kperm(c);
  float mm = s1[c]*(1.f/NN);
  float var = s2[c]*(1.f/NN) - mm*mm;
  float sc = rsqrtf(var+EPSV)*g[ac];
  avp[c] = sc;
  bvp[c] = fmaf(-mm, sc, be[ac]);
}

// ---------- aggregation (CSR gather, f16x8 lanes, 8-deep edge ILP) ----------
// Input H: row-major k-permuted (coalesced gathers). Output: chunk-panel-major
// (GEMM A operand). BN+ReLU on the INPUT fused via precomputed av/bv.
template<int K, bool BN>
__global__ __launch_bounds__(256) void k_agg16(
    const f16* __restrict__ H, const int* __restrict__ rp,
    const int* __restrict__ cs, const float* __restrict__ cf,
    const float* __restrict__ dinv2,
    const float* __restrict__ avp, const float* __restrict__ bvp,
    f16* __restrict__ outp)
{
  const int tid = threadIdx.x;
  int node, c;
  if (K == 256){
    node = blockIdx.x*8 + (tid>>5);
    c = (tid&31)*8;
  } else {
    node = blockIdx.x*4 + (tid>>6);
    c = (blockIdx.y<<9) + (tid&63)*8;
  }
  if (node >= NN) return;
  float av[8], bv[8];
  if (BN){
    f32x4 a0 = *(const f32x4*)(avp + c), a1 = *(const f32x4*)(avp + c + 4);
    f32x4 b0 = *(const f32x4*)(bvp + c), b1 = *(const f32x4*)(bvp + c + 4);
    #pragma unroll
    for (int j=0;j<4;++j){ av[j] = a0[j]; av[j+4] = a1[j]; bv[j] = b0[j]; bv[j+4] = b1[j]; }
  }
  const f16* __restrict__ Hc = H + c;
  f16x8 hv = *(const f16x8*)(Hc + (size_t)node*K);
  float d2 = dinv2[node];
  float acc[8];
  #pragma unroll
  for (int j=0;j<8;++j){
    float v = (float)hv[j];
    if (BN){ v = fmaf(v, av[j], bv[j]); v = v > 0.f ? v : 0.f; }
    acc[j] = d2*v;
  }
  const int e0 = rp[node], e1 = rp[node+1];
  int e = e0;
  for (; e + 8 <= e1; e += 8){
    int   si[8]; float wi[8]; f16x8 vi[8];
    #pragma unroll
    for (int u=0;u<8;++u){ si[u] = cs[e+u]; wi[u] = cf[e+u]; }
    #pragma unroll
    for (int u=0;u<8;++u) vi[u] = *(const f16x8*)(Hc + (size_t)si[u]*K);
    #pragma unroll
    for (int u=0;u<8;++u){
      #pragma unroll
      for (int j=0;j<8;++j){
        float a = (float)vi[u][j];
        if (BN){ a = fmaf(a, av[j], bv[j]); a = a > 0.f ? a : 0.f; }
        acc[j] = fmaf(wi[u], a, acc[j]);
      }
    }
  }
  for (; e + 4 <= e1; e += 4){
    int   s0 = cs[e],   s1i = cs[e+1], s2i = cs[e+2], s3 = cs[e+3];
    float w0 = cf[e],   w1  = cf[e+1], w2  = cf[e+2], w3 = cf[e+3];
    f16x8 v0 = *(const f16x8*)(Hc + (size_t)s0 *K);
    f16x8 v1 = *(const f16x8*)(Hc + (size_t)s1i*K);
    f16x8 v2 = *(const f16x8*)(Hc + (size_t)s2i*K);
    f16x8 v3 = *(const f16x8*)(Hc + (size_t)s3 *K);
    #pragma unroll
    for (int j=0;j<8;++j){
      float a0 = (float)v0[j], a1 = (float)v1[j], a2 = (float)v2[j], a3 = (float)v3[j];
      if (BN){
        a0 = fmaf(a0, av[j], bv[j]); a0 = a0 > 0.f ? a0 : 0.f;
        a1 = fmaf(a1, av[j], bv[j]); a1 = a1 > 0.f ? a1 : 0.f;
        a2 = fmaf(a2, av[j], bv[j]); a2 = a2 > 0.f ? a2 : 0.f;
        a3 = fmaf(a3, av[j], bv[j]); a3 = a3 > 0.f ? a3 : 0.f;
      }
      acc[j] = fmaf(w0, a0, acc[j]);
      acc[j] = fmaf(w1, a1, acc[j]);
      acc[j] = fmaf(w2, a2, acc[j]);
      acc[j] = fmaf(w3, a3, acc[j]);
    }
  }
  for (; e < e1; ++e){
    int s = cs[e]; float w = cf[e];
    f16x8 v8 = *(const f16x8*)(Hc + (size_t)s*K);
    #pragma unroll
    for (int j=0;j<8;++j){
      float v = (float)v8[j];
      if (BN){ v = fmaf(v, av[j], bv[j]); v = v > 0.f ? v : 0.f; }
      acc[j] = fmaf(w, v, acc[j]);
    }
  }
  f16x8 o;
  #pragma unroll
  for (int j=0;j<8;++j) o[j] = (f16)acc[j];
  *(f16x8*)(outp + cpm(node, c, K)) = o;   // chunk-panel-major (c 8-aligned)
}

// ---------- fp16 MFMA GEMM, 256x128 tile, 256 thr (4 waves 2Mx2N), BK=32 ----------
// R21: same per-wave 128x64 geometry and chunk-panel layout as R17/R20, but
// block col-width halved -> LDS 48KB -> 3 blocks/CU (was 2). The working
// pipeline is inter-block overlap (R7 vs R8/R9); this adds one independent
// K-stream per CU. Staging stays contiguous per instruction (A: 1 chunk/issue,
// rows=tid; B: half-chunk per wave, 1KB/instr). Plain 2-phase dbuf.
// Bijective XCD stripe map (nwg%8==0 for gx=4/8/24 x gy=196).
template<bool STATS>
__global__ __launch_bounds__(256,3) void k_gemm128(
    const f16* __restrict__ A, const f16* __restrict__ B,
    const float* __restrict__ bias, float* __restrict__ Cf,
    f16* __restrict__ Ch, float* __restrict__ s1, float* __restrict__ s2,
    int K, int M)
{
  __shared__ f16 Ah[2][8192];   // 4 chunks x 256 rows x 8 f16 (16KB/buf)
  __shared__ f16 Bh[2][4096];   // 4 chunks x 128 rows x 8 f16 (8KB/buf)
  const int tid  = threadIdx.x;
  const int lane = tid & 63;
  const int wave = tid >> 6;          // 0..3
  const int wr = wave >> 1;           // 0..1 (row half, 128 rows)
  const int wc = wave & 1;            // 0..1 (col half, 64 cols)

  const int gx = gridDim.x, gy = gridDim.y;
  int bid = blockIdx.y*gx + blockIdx.x;
  int nwg8 = (gx*gy) >> 3;
  int L = (bid & 7)*nwg8 + (bid >> 3);    // bijective when nwg%8==0
  const int by = L / gx, bx = L % gx;
  const int row0 = by*256, col0 = bx*128;

  const f16* Apan = A + (size_t)by*256*K;
  // B cols bx*128..+127 = half of 256-row panel (bx>>1), half-offset (bx&1)*1024
  const f16* Bpan = B + (size_t)(bx>>1)*256*K + (size_t)(bx&1)*1024;

  f32x16 acc[4][2];
  #pragma unroll
  for (int m=0;m<4;++m)
    #pragma unroll
    for (int n=0;n<2;++n)
      #pragma unroll
      for (int t=0;t<16;++t) acc[m][n][t] = 0.f;

  auto stage = [&](int buf, int t){
    #pragma unroll
    for (int i=0;i<4;++i){            // A: chunk i, rows = tid
      const f16* srcA = Apan + (size_t)t*8192 + i*2048 + tid*8;
      f16* dstA = &Ah[buf][i*2048 + (wave<<9)];   // wave-uniform
      __builtin_amdgcn_global_load_lds((const unsigned int*)srcA, (unsigned int*)dstA, 16, 0, 0);
    }
    #pragma unroll
    for (int i=0;i<2;++i){            // B: chunk = i*2 + (tid>>7), row = tid&127
      int slot = i*2 + (tid>>7);
      const f16* srcB = Bpan + (size_t)(4*t + slot)*2048 + (size_t)(tid&127)*8;
      f16* dstB = &Bh[buf][slot*1024 + ((wave&1)<<9)];  // wave-uniform
      __builtin_amdgcn_global_load_lds((const unsigned int*)srcB, (unsigned int*)dstB, 16, 0, 0);
    }
  };

  stage(0, 0);
  __syncthreads();
  const int nT = K >> 5;                 // BK=32
  for (int t = 0; t < nT; ++t){
    const int cur = t & 1;
    if (t + 1 < nT) stage(cur^1, t+1);

    const int hg = lane >> 5;
    const int rl = lane & 31;
    #pragma unroll
    for (int c2=0;c2<2;++c2){
      const int u = c2*2 + hg;           // 16B chunk slot 0..3
      f16x8 fa[4], fb[2];
      #pragma unroll
      for (int m=0;m<4;++m){
        int r = wr*128 + m*32 + rl;
        fa[m] = *(const f16x8*)&Ah[cur][u*2048 + r*8];
      }
      #pragma unroll
      for (int n=0;n<2;++n){
        int r = wc*64 + n*32 + rl;
        fb[n] = *(const f16x8*)&Bh[cur][u*1024 + r*8];
      }
      #pragma unroll
      for (int m=0;m<4;++m)
        #pragma unroll
        for (int n=0;n<2;++n)
          acc[m][n] = __builtin_amdgcn_mfma_f32_32x32x16_f16(fa[m], fb[n], acc[m][n], 0,0,0);
    }
    __syncthreads();
  }

  // epilogue: C/D 32x32 layout col=lane&31, row=(t&3)+8*((t>>2)&3)+4*(lane>>5)
  #pragma unroll
  for (int n=0;n<2;++n){
    int cg = col0 + wc*64 + n*32 + (lane&31);   // ACTUAL output column
    if (STATS){
      int cp = kperm(cg);                       // STORED (permuted) position
      float sum = 0.f, sq = 0.f;
      #pragma unroll
      for (int m=0;m<4;++m){
        #pragma unroll
        for (int t=0;t<16;++t){
          int rg = row0 + wr*128 + m*32 + (t&3) + ((t>>2)&3)*8 + ((lane>>5)<<2);
          if (rg < NN){
            float v = acc[m][n][t];
            sum += v; sq += v*v;
            Ch[(size_t)rg*M + cp] = (f16)v;
          }
        }
      }
      atomicAdd(&s1[cp], sum);
      atomicAdd(&s2[cp], sq);
    } else {
      float bv = (cg < M) ? bias[cg] : 0.f;
      #pragma unroll
      for (int m=0;m<4;++m){
        #pragma unroll
        for (int t=0;t<16;++t){
          int rg = row0 + wr*128 + m*32 + (t&3) + ((t>>2)&3)*8 + ((lane>>5)<<2);
          if (rg < NN && cg < M)
            __builtin_nontemporal_store(acc[m][n][t] + bv, &Cf[(size_t)rg*M + cg]);
        }
      }
    }
  }
}

extern "C" void kernel_launch(void* const* d_in, const int* in_sizes, int n_in,
                              void* d_out, int out_size, void* d_ws, size_t ws_size,
                              hipStream_t stream){
  const float* x   = (const float*)d_in[0];
  const int*   ei  = (const int*)d_in[1];
  const float* ea  = (const float*)d_in[2];
  const float* W1  = (const float*)d_in[4];
  const float* g1  = (const float*)d_in[6];
  const float* be1 = (const float*)d_in[7];
  const float* W2  = (const float*)d_in[8];
  const float* g2  = (const float*)d_in[10];
  const float* be2 = (const float*)d_in[11];
  const float* W3  = (const float*)d_in[12];
  const float* b3  = (const float*)d_in[13];
  float* out = (float*)d_out;

  // ---- workspace ----
  char* p = (char*)d_ws;
  int*   cnt    = (int*)p;   p += (size_t)NN*4;
  int*   cursor = (int*)p;   p += (size_t)NN*4;
  int*   rowptr = (int*)p;   p += (size_t)(NN+4)*4;
  float* deg    = (float*)p; p += (size_t)NN*4;
  float* dinv   = (float*)p; p += (size_t)NN*4;
  float* dinv2  = (float*)p; p += (size_t)NN*4;
  int*   csrc   = (int*)p;   p += (size_t)NE*4;
  float* ccf    = (float*)p; p += (size_t)NE*4;
  f16*   Wt     = (f16*)p;   p += (size_t)3072*1024*2;
  float* s1a    = (float*)p; p += 1024*4;   // layer-1 stats (512 used)
  float* s2a    = (float*)p; p += 1024*4;
  float* s1b    = (float*)p; p += 1024*4;   // layer-2 stats
  float* s2b    = (float*)p; p += 1024*4;
  float* avp    = (float*)p; p += 1024*4;   // BN affine scale (stored col)
  float* bvp    = (float*)p; p += 1024*4;   // BN affine shift
  f16*   aggh   = (f16*)p;   p += (size_t)50176*1024*2;  // 196 panels x 256 rows

  // ---- stage in d_out (dead before final GEMM rewrites d_out) ----
  f16* xh  = (f16*)out;                    // NN*256 f16 (row-major kperm'd)
  f16* h1h = xh  + (size_t)NN*256;         // NN*512 f16  (row-major kperm'd)
  f16* h2h = h1h + (size_t)NN*512;         // NN*1024 f16 (row-major kperm'd)

  const int T = 256;
  const int gN = (NN+T-1)/T, gE = NE/T;
  const int GR = 196;          // 50176 padded rows = 196*256

  // graph prep
  hipMemsetAsync(cnt, 0, (size_t)NN*4, stream);
  hipMemsetAsync(s1a, 0, 4*1024*4, stream);   // zero all four stat buffers
  k_init_deg<<<gN,T,0,stream>>>(deg);
  k_build<<<gE,T,0,stream>>>(ei, ea, cnt, deg);
  k_fin_deg<<<gN,T,0,stream>>>(deg, dinv, dinv2);
  k_scan<<<1,1024,0,stream>>>(cnt, rowptr, cursor);
  k_fill<<<gE,T,0,stream>>>(ei, ea, dinv, cursor, csrc, ccf);
  k_xconv<<<(NN*64+T-1)/T,T,0,stream>>>(x, xh);

  // ----- layer 1: agg(x) -> GEMM1 (f16 permuted out + stats) -----
  k_agg16<256,false><<<dim3(NN/8,1),T,0,stream>>>(xh, rowptr, csrc, ccf, dinv2,
                                                  nullptr,nullptr, aggh);
  k_w16<<<(256*512)/T,T,0,stream>>>(W1, Wt, 256, 512, 512);
  k_gemm128<true><<<dim3(4,GR),T,0,stream>>>(aggh, Wt, nullptr, nullptr, h1h, s1a, s2a, 256, 512);

  // ----- layer 2: agg(BN(h1)) -> GEMM2 (f16 permuted out + stats) -----
  k_bnpre<<<2,T,0,stream>>>(s1a, s2a, g1, be1, avp, bvp, 512);
  k_agg16<512,true><<<dim3(NN/4,1),T,0,stream>>>(h1h, rowptr, csrc, ccf, dinv2,
                                                 avp, bvp, aggh);
  k_w16<<<(512*1024)/T,T,0,stream>>>(W2, Wt, 512, 1024, 1024);
  k_gemm128<true><<<dim3(8,GR),T,0,stream>>>(aggh, Wt, nullptr, nullptr, h2h, s1b, s2b, 512, 1024);

  // ----- layer 3: agg(BN(h2)) -> GEMM3 (f32 out + b3, nt stores) -----
  k_bnpre<<<4,T,0,stream>>>(s1b, s2b, g2, be2, avp, bvp, 1024);
  k_agg16<1024,true><<<dim3(NN/4,2),T,0,stream>>>(h2h, rowptr, csrc, ccf, dinv2,
                                                  avp, bvp, aggh);
  k_w16<<<(1024*3072)/T,T,0,stream>>>(W3, Wt, 1024, 3000, 3072);
  k_gemm128<false><<<dim3(24,GR),T,0,stream>>>(aggh, Wt, b3, out, nullptr, nullptr, nullptr, 1024, 3000);
}

// Round 22
// 1406.181 us; speedup vs baseline: 1.0103x; 1.0103x over previous
//
#include <hip/hip_runtime.h>

#define NN 50000
#define NE 800000
#define EPSV 1e-5f

typedef _Float16 f16;
typedef __attribute__((ext_vector_type(4)))  float f32x4;
typedef __attribute__((ext_vector_type(16))) float f32x16;
typedef __attribute__((ext_vector_type(8)))  f16 f16x8;
typedef __attribute__((ext_vector_type(4)))  f16 f16x4;

// permuted k order within each 16-group: quads [0,2,1,3] so each MFMA fragment
// is one contiguous 16B chunk. involution; preserves offset within a quad.
static __device__ __forceinline__ int kperm(int k){
  int q = (k>>2)&3;
  int p = ((q&1)<<1) | (q>>1);
  return (k & ~15) + (p<<2) + (k&3);
}

// chunk-panel-major address for GEMM operands (A=aggh, B=Wt):
// [panel = row>>8][k-chunk = kk>>3][row&255][kk&7], panel stride 256*K.
static __device__ __forceinline__ size_t cpm(int row, int kk, int K){
  return ((size_t)(row>>8))*256*K + ((size_t)(kk>>3))*2048 + (size_t)((row&255)*8) + (kk&7);
}

// ---------- degree / CSR build ----------
__global__ void k_init_deg(float* __restrict__ deg){
  int i = blockIdx.x*256 + threadIdx.x;
  if (i < NN) deg[i] = 1.0f;
}

__global__ void k_build(const int* __restrict__ ei, const float* __restrict__ ea,
                        int* __restrict__ cnt, float* __restrict__ deg){
  int e = blockIdx.x*256 + threadIdx.x;
  if (e < NE){
    int d = ei[NE + e];
    atomicAdd(&cnt[d], 1);
    atomicAdd(&deg[d], ea[3*e+2]);
  }
}

__global__ void k_fin_deg(const float* __restrict__ deg, float* __restrict__ dinv,
                          float* __restrict__ dinv2){
  int i = blockIdx.x*256 + threadIdx.x;
  if (i < NN){ float r = rsqrtf(deg[i]); dinv[i] = r; dinv2[i] = r*r; }
}

__global__ __launch_bounds__(1024) void k_scan(const int* __restrict__ cnt,
                                               int* __restrict__ rowptr,
                                               int* __restrict__ cursor){
  __shared__ int sums[1024];
  int t = threadIdx.x;
  int b0 = t*49, b1 = b0+49; if (b0 > NN) b0 = NN; if (b1 > NN) b1 = NN;
  int s = 0;
  for (int i = b0; i < b1; ++i) s += cnt[i];
  sums[t] = s; __syncthreads();
  for (int o = 1; o < 1024; o <<= 1){
    int v = (t >= o) ? sums[t-o] : 0;
    __syncthreads();
    sums[t] += v;
    __syncthreads();
  }
  int p = sums[t] - s;
  for (int i = b0; i < b1; ++i){ rowptr[i] = p; cursor[i] = p; p += cnt[i]; }
  if (t == 1023) rowptr[NN] = sums[1023];
}

__global__ void k_fill(const int* __restrict__ ei, const float* __restrict__ ea,
                       const float* __restrict__ dinv, int* __restrict__ cursor,
                       int* __restrict__ csrc, float* __restrict__ ccf){
  int e = blockIdx.x*256 + threadIdx.x;
  if (e < NE){
    int s = ei[e], d = ei[NE+e];
    float w = ea[3*e+2];
    int p = atomicAdd(&cursor[d], 1);
    csrc[p] = s;
    ccf[p] = dinv[s]*w*dinv[d];
  }
}

// ---------- x f32 -> fp16 (row-major, k-permuted; agg1 input) ----------
__global__ void k_xconv(const float* __restrict__ x, f16* __restrict__ xh){
  int idx = blockIdx.x*256 + threadIdx.x;      // quad index
  if (idx >= NN*64) return;
  int node = idx >> 6, k = (idx & 63)*4;
  f32x4 v = *(const f32x4*)(x + (size_t)node*256 + k);
  f16x4 h;
  #pragma unroll
  for (int j=0;j<4;++j) h[j] = (f16)v[j];
  *(f16x4*)(xh + (size_t)node*256 + kperm(k)) = h;
}

// ---------- W transpose -> fp16 chunk-panel-major [n-panel][kchunk][n][8] ----------
__global__ void k_w16(const float* __restrict__ W, f16* __restrict__ Wt,
                      int K, int M, int Mpad){
  int idx = blockIdx.x*256 + threadIdx.x;
  if (idx >= K*Mpad) return;
  int k = idx / Mpad, n = idx % Mpad;
  float v = (n < M) ? W[(size_t)k*M + n] : 0.f;
  Wt[cpm(n, kperm(k), K)] = (f16)v;
}

// ---------- BN affine precompute: av/bv per STORED column ----------
__global__ void k_bnpre(const float* __restrict__ s1, const float* __restrict__ s2,
                        const float* __restrict__ g, const float* __restrict__ be,
                        float* __restrict__ avp, float* __restrict__ bvp, int H){
  int c = blockIdx.x*256 + threadIdx.x;
  if (c >= H) return;
  int ac = kperm(c);
  float mm = s1[c]*(1.f/NN);
  float var = s2[c]*(1.f/NN) - mm*mm;
  float sc = rsqrtf(var+EPSV)*g[ac];
  avp[c] = sc;
  bvp[c] = fmaf(-mm, sc, be[ac]);
}

// ---------- aggregation (CSR gather, f16x8 lanes, 8-deep edge ILP) ----------
// Input H: row-major k-permuted (coalesced gathers). Output: chunk-panel-major
// (GEMM A operand). BN+ReLU on the INPUT fused via precomputed av/bv.
template<int K, bool BN>
__global__ __launch_bounds__(256) void k_agg16(
    const f16* __restrict__ H, const int* __restrict__ rp,
    const int* __restrict__ cs, const float* __restrict__ cf,
    const float* __restrict__ dinv2,
    const float* __restrict__ avp, const float* __restrict__ bvp,
    f16* __restrict__ outp)
{
  const int tid = threadIdx.x;
  int node, c;
  if (K == 256){
    node = blockIdx.x*8 + (tid>>5);
    c = (tid&31)*8;
  } else {
    node = blockIdx.x*4 + (tid>>6);
    c = (blockIdx.y<<9) + (tid&63)*8;
  }
  if (node >= NN) return;
  float av[8], bv[8];
  if (BN){
    f32x4 a0 = *(const f32x4*)(avp + c), a1 = *(const f32x4*)(avp + c + 4);
    f32x4 b0 = *(const f32x4*)(bvp + c), b1 = *(const f32x4*)(bvp + c + 4);
    #pragma unroll
    for (int j=0;j<4;++j){ av[j] = a0[j]; av[j+4] = a1[j]; bv[j] = b0[j]; bv[j+4] = b1[j]; }
  }
  const f16* __restrict__ Hc = H + c;
  f16x8 hv = *(const f16x8*)(Hc + (size_t)node*K);
  float d2 = dinv2[node];
  float acc[8];
  #pragma unroll
  for (int j=0;j<8;++j){
    float v = (float)hv[j];
    if (BN){ v = fmaf(v, av[j], bv[j]); v = v > 0.f ? v : 0.f; }
    acc[j] = d2*v;
  }
  const int e0 = rp[node], e1 = rp[node+1];
  int e = e0;
  for (; e + 8 <= e1; e += 8){
    int   si[8]; float wi[8]; f16x8 vi[8];
    #pragma unroll
    for (int u=0;u<8;++u){ si[u] = cs[e+u]; wi[u] = cf[e+u]; }
    #pragma unroll
    for (int u=0;u<8;++u) vi[u] = *(const f16x8*)(Hc + (size_t)si[u]*K);
    #pragma unroll
    for (int u=0;u<8;++u){
      #pragma unroll
      for (int j=0;j<8;++j){
        float a = (float)vi[u][j];
        if (BN){ a = fmaf(a, av[j], bv[j]); a = a > 0.f ? a : 0.f; }
        acc[j] = fmaf(wi[u], a, acc[j]);
      }
    }
  }
  for (; e + 4 <= e1; e += 4){
    int   s0 = cs[e],   s1i = cs[e+1], s2i = cs[e+2], s3 = cs[e+3];
    float w0 = cf[e],   w1  = cf[e+1], w2  = cf[e+2], w3 = cf[e+3];
    f16x8 v0 = *(const f16x8*)(Hc + (size_t)s0 *K);
    f16x8 v1 = *(const f16x8*)(Hc + (size_t)s1i*K);
    f16x8 v2 = *(const f16x8*)(Hc + (size_t)s2i*K);
    f16x8 v3 = *(const f16x8*)(Hc + (size_t)s3 *K);
    #pragma unroll
    for (int j=0;j<8;++j){
      float a0 = (float)v0[j], a1 = (float)v1[j], a2 = (float)v2[j], a3 = (float)v3[j];
      if (BN){
        a0 = fmaf(a0, av[j], bv[j]); a0 = a0 > 0.f ? a0 : 0.f;
        a1 = fmaf(a1, av[j], bv[j]); a1 = a1 > 0.f ? a1 : 0.f;
        a2 = fmaf(a2, av[j], bv[j]); a2 = a2 > 0.f ? a2 : 0.f;
        a3 = fmaf(a3, av[j], bv[j]); a3 = a3 > 0.f ? a3 : 0.f;
      }
      acc[j] = fmaf(w0, a0, acc[j]);
      acc[j] = fmaf(w1, a1, acc[j]);
      acc[j] = fmaf(w2, a2, acc[j]);
      acc[j] = fmaf(w3, a3, acc[j]);
    }
  }
  for (; e < e1; ++e){
    int s = cs[e]; float w = cf[e];
    f16x8 v8 = *(const f16x8*)(Hc + (size_t)s*K);
    #pragma unroll
    for (int j=0;j<8;++j){
      float v = (float)v8[j];
      if (BN){ v = fmaf(v, av[j], bv[j]); v = v > 0.f ? v : 0.f; }
      acc[j] = fmaf(w, v, acc[j]);
    }
  }
  f16x8 o;
  #pragma unroll
  for (int j=0;j<8;++j) o[j] = (f16)acc[j];
  *(f16x8*)(outp + cpm(node, c, K)) = o;   // chunk-panel-major (c 8-aligned)
}

// ---------- fp16 MFMA GEMM, 256x256 tile, 512 thr (8 waves 2Mx4N), BK=32 ----------
// FINAL (R20/R17 config, best measured: GEMM3 505-511us, 0 bank conflicts).
// Chunk-panel-major operands -> contiguous 8KB stage issues + conflict-free
// chunk-major LDS. Plain 2-phase dbuf (7 schedule variants + 3 geometry cells
// all lost to this). 64KB LDS -> 2 blocks/CU (inter-block overlap = the
// working pipeline). Bijective XCD stripe map (nwg%8==0).
template<bool STATS>
__global__ __launch_bounds__(512,2) void k_gemm512(
    const f16* __restrict__ A, const f16* __restrict__ B,
    const float* __restrict__ bias, float* __restrict__ Cf,
    f16* __restrict__ Ch, float* __restrict__ s1, float* __restrict__ s2,
    int K, int M)
{
  __shared__ f16 Ah[2][8192];   // [buf][slot*2048 + row*8], 4 slots of 16B-chunks
  __shared__ f16 Bh[2][8192];
  const int tid  = threadIdx.x;
  const int lane = tid & 63;
  const int wave = tid >> 6;          // 0..7
  const int wr = wave >> 2;           // 0..1 (row half, 128 rows)
  const int wc = wave & 3;            // 0..3 (col quarter, 64 cols)

  const int gx = gridDim.x, gy = gridDim.y;
  int bid = blockIdx.y*gx + blockIdx.x;
  int nwg8 = (gx*gy) >> 3;
  int L = (bid & 7)*nwg8 + (bid >> 3);    // bijective when nwg%8==0
  const int by = L / gx, bx = L % gx;
  const int row0 = by*256, col0 = bx*256;

  const f16* Apan = A + (size_t)by*256*K;
  const f16* Bpan = B + (size_t)bx*256*K;

  f32x16 acc[4][2];
  #pragma unroll
  for (int m=0;m<4;++m)
    #pragma unroll
    for (int n=0;n<2;++n)
      #pragma unroll
      for (int t=0;t<16;++t) acc[m][n][t] = 0.f;

  auto stage = [&](int buf, int t){
    #pragma unroll
    for (int i=0;i<2;++i){
      const f16* srcA = Apan + (size_t)t*8192 + i*4096 + tid*8;
      const f16* srcB = Bpan + (size_t)t*8192 + i*4096 + tid*8;
      f16* dstA = &Ah[buf][i*4096 + (wave<<9)];   // wave-uniform, linear
      f16* dstB = &Bh[buf][i*4096 + (wave<<9)];
      __builtin_amdgcn_global_load_lds((const unsigned int*)srcA, (unsigned int*)dstA, 16, 0, 0);
      __builtin_amdgcn_global_load_lds((const unsigned int*)srcB, (unsigned int*)dstB, 16, 0, 0);
    }
  };

  stage(0, 0);
  __syncthreads();
  const int nT = K >> 5;                 // BK=32
  for (int t = 0; t < nT; ++t){
    const int cur = t & 1;
    if (t + 1 < nT) stage(cur^1, t+1);

    const int hg = lane >> 5;
    const int rl = lane & 31;
    #pragma unroll
    for (int c2=0;c2<2;++c2){
      const int u = c2*2 + hg;           // 16B chunk slot 0..3
      f16x8 fa[4], fb[2];
      #pragma unroll
      for (int m=0;m<4;++m){
        int r = wr*128 + m*32 + rl;
        fa[m] = *(const f16x8*)&Ah[cur][u*2048 + r*8];
      }
      #pragma unroll
      for (int n=0;n<2;++n){
        int r = wc*64 + n*32 + rl;
        fb[n] = *(const f16x8*)&Bh[cur][u*2048 + r*8];
      }
      #pragma unroll
      for (int m=0;m<4;++m)
        #pragma unroll
        for (int n=0;n<2;++n)
          acc[m][n] = __builtin_amdgcn_mfma_f32_32x32x16_f16(fa[m], fb[n], acc[m][n], 0,0,0);
    }
    __syncthreads();
  }

  // epilogue: C/D 32x32 layout col=lane&31, row=(t&3)+8*((t>>2)&3)+4*(lane>>5)
  #pragma unroll
  for (int n=0;n<2;++n){
    int cg = col0 + wc*64 + n*32 + (lane&31);   // ACTUAL output column
    if (STATS){
      int cp = kperm(cg);                       // STORED (permuted) position
      float sum = 0.f, sq = 0.f;
      #pragma unroll
      for (int m=0;m<4;++m){
        #pragma unroll
        for (int t=0;t<16;++t){
          int rg = row0 + wr*128 + m*32 + (t&3) + ((t>>2)&3)*8 + ((lane>>5)<<2);
          if (rg < NN){
            float v = acc[m][n][t];
            sum += v; sq += v*v;
            Ch[(size_t)rg*M + cp] = (f16)v;
          }
        }
      }
      atomicAdd(&s1[cp], sum);
      atomicAdd(&s2[cp], sq);
    } else {
      float bv = (cg < M) ? bias[cg] : 0.f;
      #pragma unroll
      for (int m=0;m<4;++m){
        #pragma unroll
        for (int t=0;t<16;++t){
          int rg = row0 + wr*128 + m*32 + (t&3) + ((t>>2)&3)*8 + ((lane>>5)<<2);
          if (rg < NN && cg < M)
            __builtin_nontemporal_store(acc[m][n][t] + bv, &Cf[(size_t)rg*M + cg]);
        }
      }
    }
  }
}

extern "C" void kernel_launch(void* const* d_in, const int* in_sizes, int n_in,
                              void* d_out, int out_size, void* d_ws, size_t ws_size,
                              hipStream_t stream){
  const float* x   = (const float*)d_in[0];
  const int*   ei  = (const int*)d_in[1];
  const float* ea  = (const float*)d_in[2];
  const float* W1  = (const float*)d_in[4];
  const float* g1  = (const float*)d_in[6];
  const float* be1 = (const float*)d_in[7];
  const float* W2  = (const float*)d_in[8];
  const float* g2  = (const float*)d_in[10];
  const float* be2 = (const float*)d_in[11];
  const float* W3  = (const float*)d_in[12];
  const float* b3  = (const float*)d_in[13];
  float* out = (float*)d_out;

  // ---- workspace ----
  char* p = (char*)d_ws;
  int*   cnt    = (int*)p;   p += (size_t)NN*4;
  int*   cursor = (int*)p;   p += (size_t)NN*4;
  int*   rowptr = (int*)p;   p += (size_t)(NN+4)*4;
  float* deg    = (float*)p; p += (size_t)NN*4;
  float* dinv   = (float*)p; p += (size_t)NN*4;
  float* dinv2  = (float*)p; p += (size_t)NN*4;
  int*   csrc   = (int*)p;   p += (size_t)NE*4;
  float* ccf    = (float*)p; p += (size_t)NE*4;
  f16*   Wt     = (f16*)p;   p += (size_t)3072*1024*2;
  float* s1a    = (float*)p; p += 1024*4;   // layer-1 stats (512 used)
  float* s2a    = (float*)p; p += 1024*4;
  float* s1b    = (float*)p; p += 1024*4;   // layer-2 stats
  float* s2b    = (float*)p; p += 1024*4;
  float* avp    = (float*)p; p += 1024*4;   // BN affine scale (stored col)
  float* bvp    = (float*)p; p += 1024*4;   // BN affine shift
  f16*   aggh   = (f16*)p;   p += (size_t)50176*1024*2;  // 196 panels x 256 rows

  // ---- stage in d_out (dead before final GEMM rewrites d_out) ----
  f16* xh  = (f16*)out;                    // NN*256 f16 (row-major kperm'd)
  f16* h1h = xh  + (size_t)NN*256;         // NN*512 f16  (row-major kperm'd)
  f16* h2h = h1h + (size_t)NN*512;         // NN*1024 f16 (row-major kperm'd)

  const int T = 256;
  const int gN = (NN+T-1)/T, gE = NE/T;
  const int GR = 196;          // 50176 padded rows = 196*256

  // graph prep
  hipMemsetAsync(cnt, 0, (size_t)NN*4, stream);
  hipMemsetAsync(s1a, 0, 4*1024*4, stream);   // zero all four stat buffers
  k_init_deg<<<gN,T,0,stream>>>(deg);
  k_build<<<gE,T,0,stream>>>(ei, ea, cnt, deg);
  k_fin_deg<<<gN,T,0,stream>>>(deg, dinv, dinv2);
  k_scan<<<1,1024,0,stream>>>(cnt, rowptr, cursor);
  k_fill<<<gE,T,0,stream>>>(ei, ea, dinv, cursor, csrc, ccf);
  k_xconv<<<(NN*64+T-1)/T,T,0,stream>>>(x, xh);

  // ----- layer 1: agg(x) -> GEMM1 (f16 permuted out + stats) -----
  k_agg16<256,false><<<dim3(NN/8,1),T,0,stream>>>(xh, rowptr, csrc, ccf, dinv2,
                                                  nullptr,nullptr, aggh);
  k_w16<<<(256*512)/T,T,0,stream>>>(W1, Wt, 256, 512, 512);
  k_gemm512<true><<<dim3(2,GR),512,0,stream>>>(aggh, Wt, nullptr, nullptr, h1h, s1a, s2a, 256, 512);

  // ----- layer 2: agg(BN(h1)) -> GEMM2 (f16 permuted out + stats) -----
  k_bnpre<<<2,T,0,stream>>>(s1a, s2a, g1, be1, avp, bvp, 512);
  k_agg16<512,true><<<dim3(NN/4,1),T,0,stream>>>(h1h, rowptr, csrc, ccf, dinv2,
                                                 avp, bvp, aggh);
  k_w16<<<(512*1024)/T,T,0,stream>>>(W2, Wt, 512, 1024, 1024);
  k_gemm512<true><<<dim3(4,GR),512,0,stream>>>(aggh, Wt, nullptr, nullptr, h2h, s1b, s2b, 512, 1024);

  // ----- layer 3: agg(BN(h2)) -> GEMM3 (f32 out + b3, nt stores) -----
  k_bnpre<<<4,T,0,stream>>>(s1b, s2b, g2, be2, avp, bvp, 1024);
  k_agg16<1024,true><<<dim3(NN/4,2),T,0,stream>>>(h2h, rowptr, csrc, ccf, dinv2,
                                                  avp, bvp, aggh);
  k_w16<<<(1024*3072)/T,T,0,stream>>>(W3, Wt, 1024, 3000, 3072);
  k_gemm512<false><<<dim3(12,GR),512,0,stream>>>(aggh, Wt, b3, out, nullptr, nullptr, nullptr, 1024, 3000);
}